// Round 11
// baseline (217.821 us; speedup 1.0000x reference)
//
#include <hip/hip_runtime.h>

typedef unsigned char u8;
typedef signed char s8;
typedef unsigned int u32;
typedef __attribute__((ext_vector_type(4))) int i32x4;

#define M_TOK 8192
#define N_OUT 4096
#define K_IN  4096
#define NT    32          // K-tiles of BK=128 int8

// ---------------------------------------------------------------------------
// Fused pre-pass: blocks [0,8192) = per-row absmax quantize x fp32->int8;
// blocks [8192,8704) = unpack int4 (byte-per-int32) -> int8 [O][I]
// ---------------------------------------------------------------------------
static __device__ __forceinline__ u32 pack4(float4 v, float inv) {
    int q0 = __float2int_rn(v.x * inv) & 255;
    int q1 = __float2int_rn(v.y * inv) & 255;
    int q2 = __float2int_rn(v.z * inv) & 255;
    int q3 = __float2int_rn(v.w * inv) & 255;
    return (u32)q0 | ((u32)q1 << 8) | ((u32)q2 << 16) | ((u32)q3 << 24);
}

__global__ __launch_bounds__(256) void prep_kernel(const float* __restrict__ x,
                                                   const int* __restrict__ pw,
                                                   s8* __restrict__ xq,
                                                   float* __restrict__ sx,
                                                   s8* __restrict__ wq) {
    __shared__ float red[4];
    int bid = blockIdx.x;
    int t = threadIdx.x;
    if (bid < M_TOK) {
        int row = bid;
        const float4* xr = (const float4*)(x + (size_t)row * K_IN);
        float4 v0 = xr[t], v1 = xr[t + 256], v2 = xr[t + 512], v3 = xr[t + 768];
        float am = 0.f;
        am = fmaxf(am, fmaxf(fmaxf(fabsf(v0.x), fabsf(v0.y)), fmaxf(fabsf(v0.z), fabsf(v0.w))));
        am = fmaxf(am, fmaxf(fmaxf(fabsf(v1.x), fabsf(v1.y)), fmaxf(fabsf(v1.z), fabsf(v1.w))));
        am = fmaxf(am, fmaxf(fmaxf(fabsf(v2.x), fabsf(v2.y)), fmaxf(fabsf(v2.z), fabsf(v2.w))));
        am = fmaxf(am, fmaxf(fmaxf(fabsf(v3.x), fabsf(v3.y)), fmaxf(fabsf(v3.z), fabsf(v3.w))));
#pragma unroll
        for (int o = 32; o > 0; o >>= 1) am = fmaxf(am, __shfl_xor(am, o));
        if ((t & 63) == 0) red[t >> 6] = am;
        __syncthreads();
        am = fmaxf(fmaxf(red[0], red[1]), fmaxf(red[2], red[3]));
        float inv = (am > 0.f) ? 127.f / am : 0.f;
        if (t == 0) sx[row] = (am > 0.f) ? am / 127.f : 0.f;
        u32* out = (u32*)(xq + (size_t)row * K_IN);
        out[t]       = pack4(v0, inv);
        out[t + 256] = pack4(v1, inv);
        out[t + 512] = pack4(v2, inv);
        out[t + 768] = pack4(v3, inv);
    } else {
        const int n4 = (N_OUT * K_IN / 2) / 4;
        int idx = (bid - M_TOK) * 256 + t;
        const int stride = 512 * 256;
        for (int i = idx; i < n4; i += stride) {
            int4 p = *(const int4*)(pw + (size_t)i * 4);
            u32 lo = (u32)(((p.x & 15) - 8) & 255)
                   | ((u32)((((p.x >> 4) & 15) - 8) & 255) << 8)
                   | ((u32)((((p.y) & 15) - 8) & 255) << 16)
                   | ((u32)((((p.y >> 4) & 15) - 8) & 255) << 24);
            u32 hi = (u32)(((p.z & 15) - 8) & 255)
                   | ((u32)((((p.z >> 4) & 15) - 8) & 255) << 8)
                   | ((u32)((((p.w) & 15) - 8) & 255) << 16)
                   | ((u32)((((p.w >> 4) & 15) - 8) & 255) << 24);
            uint2 o; o.x = lo; o.y = hi;
            *(uint2*)(wq + (size_t)i * 8) = o;
        }
    }
}

// ---------------------------------------------------------------------------
// 256x256 int8 GEMM, round-9 schedule + cross-tile read rotation:
// next tile's B-frags + first A-frags issued after the boundary barrier,
// hidden under the current tile's last MFMA burst.
// C[n][o] = sx[n] * scale[o] * sum_k xq[n][k]*wq[o][k]
// LDS: row-major [256][128] i8 per region, byte ^= (row&7)<<4 swizzle.
// ---------------------------------------------------------------------------
#define MFMA(a, b, c) __builtin_amdgcn_mfma_i32_16x16x64_i8(a, b, c, 0, 0, 0)

static __device__ __forceinline__ i32x4 ldsv(const u8* p, int idx) {
    return *(const i32x4*)(p + idx);
}

// B-frag array layout: BB[2n + kk] = frag for output-col group n, K-half kk
#define MFMA16(A00, A01, A10, A11, M0, M1, BB)            \
    acc[M0][0] = MFMA(A00, BB[0], acc[M0][0]);            \
    acc[M0][1] = MFMA(A00, BB[2], acc[M0][1]);            \
    acc[M0][2] = MFMA(A00, BB[4], acc[M0][2]);            \
    acc[M0][3] = MFMA(A00, BB[6], acc[M0][3]);            \
    acc[M1][0] = MFMA(A10, BB[0], acc[M1][0]);            \
    acc[M1][1] = MFMA(A10, BB[2], acc[M1][1]);            \
    acc[M1][2] = MFMA(A10, BB[4], acc[M1][2]);            \
    acc[M1][3] = MFMA(A10, BB[6], acc[M1][3]);            \
    acc[M0][0] = MFMA(A01, BB[1], acc[M0][0]);            \
    acc[M0][1] = MFMA(A01, BB[3], acc[M0][1]);            \
    acc[M0][2] = MFMA(A01, BB[5], acc[M0][2]);            \
    acc[M0][3] = MFMA(A01, BB[7], acc[M0][3]);            \
    acc[M1][0] = MFMA(A11, BB[1], acc[M1][0]);            \
    acc[M1][1] = MFMA(A11, BB[3], acc[M1][1]);            \
    acc[M1][2] = MFMA(A11, BB[5], acc[M1][2]);            \
    acc[M1][3] = MFMA(A11, BB[7], acc[M1][3]);

__global__ __launch_bounds__(512, 2) void gemmrot_i8_kernel(const s8* __restrict__ A,
                                                            const s8* __restrict__ B,
                                                            const float* __restrict__ sx,
                                                            const float* __restrict__ scale,
                                                            float* __restrict__ C) {
    __shared__ __align__(16) u8 lds[131072];

#define GLo(src, dstIdx)                                                        \
    __builtin_amdgcn_global_load_lds(                                           \
        (const __attribute__((address_space(1))) void*)(src),                   \
        (__attribute__((address_space(3))) void*)&lds[dstIdx], 16, 0, 0)

    int wg = blockIdx.x;
    int swz = (wg & 7) * 64 + (wg >> 3);
    int bm = swz >> 4;
    int bn = swz & 15;

    int t = threadIdx.x;
    int l = t & 63;
    int wid = t >> 6;
    int wr = wid >> 2;
    int wc = wid & 3;

    const size_t soff = (size_t)(t >> 3) * K_IN + (size_t)((((t & 7) ^ ((t >> 3) & 7)) << 4));
    const size_t S64 = (size_t)64 * K_IN;
    const int t16 = t * 16;

    const s8* Alo = A + (size_t)(bm * 256) * K_IN;
    const s8* Ahi = Alo + (size_t)128 * K_IN;
    const s8* Blo = B + (size_t)(bn * 256) * K_IN;
    const s8* Bhi = Blo + (size_t)128 * K_IN;

    const int kx = (l & 7) << 4;
    const int koff0 = (((l >> 4) << 4)) ^ kx;
    const int koff1 = koff0 ^ 64;
    const int aB = wr * 16384 + (l & 15) * 128;
    const int bB = 32768 + wc * 8192 + (l & 15) * 128;

    i32x4 acc[8][4] = {};

    // ---- prologue: B(0),A(0) -> buf0; B(1) -> buf1 ----
    GLo(Blo + soff, 32768 + t16);         GLo(Blo + soff + S64, 32768 + t16 + 8192);
    GLo(Bhi + soff, 49152 + t16);         GLo(Bhi + soff + S64, 49152 + t16 + 8192);
    GLo(Alo + soff, t16);                 GLo(Alo + soff + S64, t16 + 8192);
    GLo(Ahi + soff, 16384 + t16);         GLo(Ahi + soff + S64, 16384 + t16 + 8192);
    GLo(Blo + soff + 128, 98304 + t16);   GLo(Blo + soff + S64 + 128, 98304 + t16 + 8192);
    GLo(Bhi + soff + 128, 114688 + t16);  GLo(Bhi + soff + S64 + 128, 114688 + t16 + 8192);
    asm volatile("s_waitcnt vmcnt(4)" ::: "memory");
    __builtin_amdgcn_s_barrier();
    asm volatile("" ::: "memory");

    // ---- initial read frontier for tile 0 (buf0) ----
    i32x4 bX[8], pX[4], bY[8], pY[4];
    bX[0] = ldsv(lds, bB + koff0);        bX[1] = ldsv(lds, bB + koff1);
    bX[2] = ldsv(lds, bB + 2048 + koff0); bX[3] = ldsv(lds, bB + 2048 + koff1);
    bX[4] = ldsv(lds, bB + 4096 + koff0); bX[5] = ldsv(lds, bB + 4096 + koff1);
    bX[6] = ldsv(lds, bB + 6144 + koff0); bX[7] = ldsv(lds, bB + 6144 + koff1);
    pX[0] = ldsv(lds, aB + koff0);        pX[1] = ldsv(lds, aB + koff1);
    pX[2] = ldsv(lds, aB + 2048 + koff0); pX[3] = ldsv(lds, aB + 2048 + koff1);

// One K-tile. C/N = byte base of current/next LDS buffer. BC/PC = this tile's
// carried-in frags; BN/PN = next tile's frontier (read at the end, under the
// final MFMA burst).
#define TILE_BODY(T, Cb, Nb, BC, PC, BN, PN)                                  \
  do {                                                                        \
    if ((T) + 1 < NT) {                                                       \
      size_t ko = (size_t)((T) + 1) * 128;                                    \
      GLo(Alo + soff + ko,        (Nb) + t16);                                \
      GLo(Alo + soff + S64 + ko,  (Nb) + 8192 + t16);                         \
      GLo(Ahi + soff + ko,        (Nb) + 16384 + t16);                        \
      GLo(Ahi + soff + S64 + ko,  (Nb) + 24576 + t16);                        \
    }                                                                         \
    i32x4 q00 = ldsv(lds, (Cb) + aB + 4096 + koff0);                          \
    i32x4 q01 = ldsv(lds, (Cb) + aB + 4096 + koff1);                          \
    i32x4 q10 = ldsv(lds, (Cb) + aB + 6144 + koff0);                          \
    i32x4 q11 = ldsv(lds, (Cb) + aB + 6144 + koff1);                          \
    __builtin_amdgcn_s_setprio(1);                                            \
    MFMA16(PC[0], PC[1], PC[2], PC[3], 0, 1, BC);                             \
    __builtin_amdgcn_s_setprio(0);                                            \
    i32x4 r00 = ldsv(lds, (Cb) + aB + 8192 + koff0);                          \
    i32x4 r01 = ldsv(lds, (Cb) + aB + 8192 + koff1);                          \
    i32x4 r10 = ldsv(lds, (Cb) + aB + 10240 + koff0);                         \
    i32x4 r11 = ldsv(lds, (Cb) + aB + 10240 + koff1);                         \
    __builtin_amdgcn_s_setprio(1);                                            \
    MFMA16(q00, q01, q10, q11, 2, 3, BC);                                     \
    __builtin_amdgcn_s_setprio(0);                                            \
    __builtin_amdgcn_s_barrier();                                             \
    asm volatile("" ::: "memory");                                            \
    if ((T) + 2 < NT) {                                                       \
      size_t ko2 = (size_t)((T) + 2) * 128;                                   \
      GLo(Blo + soff + ko2,       (Cb) + 32768 + t16);                        \
      GLo(Blo + soff + S64 + ko2, (Cb) + 40960 + t16);                        \
      GLo(Bhi + soff + ko2,       (Cb) + 49152 + t16);                        \
      GLo(Bhi + soff + S64 + ko2, (Cb) + 57344 + t16);                        \
    }                                                                         \
    i32x4 s00 = ldsv(lds, (Cb) + aB + 12288 + koff0);                         \
    i32x4 s01 = ldsv(lds, (Cb) + aB + 12288 + koff1);                         \
    i32x4 s10 = ldsv(lds, (Cb) + aB + 14336 + koff0);                         \
    i32x4 s11 = ldsv(lds, (Cb) + aB + 14336 + koff1);                         \
    __builtin_amdgcn_s_setprio(1);                                            \
    MFMA16(r00, r01, r10, r11, 4, 5, BC);                                     \
    __builtin_amdgcn_s_setprio(0);                                            \
    if ((T) < NT - 2) asm volatile("s_waitcnt vmcnt(4)" ::: "memory");        \
    else              asm volatile("s_waitcnt vmcnt(0)" ::: "memory");        \
    __builtin_amdgcn_s_barrier();                                             \
    asm volatile("" ::: "memory");                                            \
    if ((T) + 1 < NT) {                                                       \
      BN[0] = ldsv(lds, (Nb) + bB + koff0);                                   \
      BN[1] = ldsv(lds, (Nb) + bB + koff1);                                   \
      BN[2] = ldsv(lds, (Nb) + bB + 2048 + koff0);                            \
      BN[3] = ldsv(lds, (Nb) + bB + 2048 + koff1);                            \
      BN[4] = ldsv(lds, (Nb) + bB + 4096 + koff0);                            \
      BN[5] = ldsv(lds, (Nb) + bB + 4096 + koff1);                            \
      BN[6] = ldsv(lds, (Nb) + bB + 6144 + koff0);                            \
      BN[7] = ldsv(lds, (Nb) + bB + 6144 + koff1);                            \
      PN[0] = ldsv(lds, (Nb) + aB + koff0);                                   \
      PN[1] = ldsv(lds, (Nb) + aB + koff1);                                   \
      PN[2] = ldsv(lds, (Nb) + aB + 2048 + koff0);                            \
      PN[3] = ldsv(lds, (Nb) + aB + 2048 + koff1);                            \
    }                                                                         \
    __builtin_amdgcn_s_setprio(1);                                            \
    MFMA16(s00, s01, s10, s11, 6, 7, BC);                                     \
    __builtin_amdgcn_s_setprio(0);                                            \
  } while (0)

    for (int T = 0; T < NT; T += 2) {
        TILE_BODY(T,     0,     65536, bX, pX, bY, pY);
        TILE_BODY(T + 1, 65536, 0,     bY, pY, bX, pX);
    }
#undef TILE_BODY

    // ---- epilogue: C/D layout col = lane&15, row = (lane>>4)*4 + reg ----
    int col0 = bn * 256 + wc * 64 + (l & 15);
    float sc_[4];
#pragma unroll
    for (int n = 0; n < 4; ++n) sc_[n] = scale[col0 + n * 16];

#pragma unroll
    for (int m = 0; m < 8; ++m) {
        int row0 = bm * 256 + wr * 128 + m * 16 + (l >> 4) * 4;
        float4 sxr = *(const float4*)(sx + row0);
        float sxa[4] = {sxr.x, sxr.y, sxr.z, sxr.w};
#pragma unroll
        for (int n = 0; n < 4; ++n) {
            int gcol = col0 + n * 16;
#pragma unroll
            for (int j = 0; j < 4; ++j)
                C[(size_t)(row0 + j) * N_OUT + gcol] = (float)acc[m][n][j] * sxa[j] * sc_[n];
        }
    }
#undef GLo
}

// ---------------------------------------------------------------------------
// Fallback (workspace too small): fused fp32 LDS-tiled GEMM
// ---------------------------------------------------------------------------
__global__ __launch_bounds__(256) void gemm_fb_kernel(const float* __restrict__ X,
                                                      const int* __restrict__ PW,
                                                      const float* __restrict__ S,
                                                      float* __restrict__ C) {
    __shared__ float sxm[64][33];
    __shared__ float swm[64][33];
    int bm = blockIdx.x / (N_OUT / 64);
    int bn = blockIdx.x % (N_OUT / 64);
    int t = threadIdx.x;
    int r = t >> 2, c8 = (t & 3) * 8;
    int tx = t & 15, ty = t >> 4;
    float acc[4][4] = {};
    for (int k0 = 0; k0 < K_IN; k0 += 32) {
        const float* xs = X + (size_t)(bm * 64 + r) * K_IN + k0 + c8;
#pragma unroll
        for (int j = 0; j < 8; ++j) sxm[r][c8 + j] = xs[j];
        const int* ps = PW + ((size_t)(bn * 64 + r) * K_IN + k0 + c8) / 2;
#pragma unroll
        for (int j = 0; j < 4; ++j) {
            int b = ps[j];
            swm[r][c8 + 2 * j]     = (float)((b & 15) - 8);
            swm[r][c8 + 2 * j + 1] = (float)(((b >> 4) & 15) - 8);
        }
        __syncthreads();
#pragma unroll
        for (int kk = 0; kk < 32; ++kk) {
            float a[4], w[4];
#pragma unroll
            for (int i = 0; i < 4; ++i) a[i] = sxm[ty * 4 + i][kk];
#pragma unroll
            for (int j = 0; j < 4; ++j) w[j] = swm[tx * 4 + j][kk];
#pragma unroll
            for (int i = 0; i < 4; ++i)
#pragma unroll
                for (int j = 0; j < 4; ++j) acc[i][j] += a[i] * w[j];
        }
        __syncthreads();
    }
#pragma unroll
    for (int i = 0; i < 4; ++i) {
        int gr = bm * 64 + ty * 4 + i;
#pragma unroll
        for (int j = 0; j < 4; ++j) {
            int gc = bn * 64 + tx * 4 + j;
            C[(size_t)gr * N_OUT + gc] = acc[i][j] * S[gc];
        }
    }
}

// ---------------------------------------------------------------------------
// Entry point
// ---------------------------------------------------------------------------
extern "C" void kernel_launch(void* const* d_in, const int* in_sizes, int n_in,
                              void* d_out, int out_size, void* d_ws, size_t ws_size,
                              hipStream_t stream) {
    const float* x  = (const float*)d_in[0];
    const int*   pw = (const int*)d_in[1];
    const float* sc = (const float*)d_in[2];
    float* out = (float*)d_out;

    const size_t xq_bytes = (size_t)M_TOK * K_IN;
    const size_t wq_bytes = (size_t)N_OUT * K_IN;
    const size_t sx_bytes = (size_t)M_TOK * sizeof(float);
    const size_t need = xq_bytes + wq_bytes + sx_bytes;

    if (ws_size >= need) {
        s8* xq = (s8*)d_ws;
        s8* wq = xq + xq_bytes;
        float* sx = (float*)(wq + wq_bytes);
        prep_kernel<<<dim3(M_TOK + 512), dim3(256), 0, stream>>>(x, pw, xq, sx, wq);
        gemmrot_i8_kernel<<<dim3((M_TOK / 256) * (N_OUT / 256)), dim3(512), 0, stream>>>(
            xq, wq, sx, sc, out);
    } else {
        gemm_fb_kernel<<<dim3((M_TOK / 64) * (N_OUT / 64)), dim3(256), 0, stream>>>(x, pw, sc, out);
    }
}

// Round 12
// 191.047 us; speedup vs baseline: 1.1401x; 1.1401x over previous
//
#include <hip/hip_runtime.h>

typedef unsigned char u8;
typedef signed char s8;
typedef unsigned int u32;
typedef __attribute__((ext_vector_type(4))) int i32x4;
typedef __attribute__((ext_vector_type(16))) int i32x16;

#define M_TOK 8192
#define N_OUT 4096
#define K_IN  4096
#define NT    32          // K-tiles of BK=128 int8

// ---------------------------------------------------------------------------
// Fused pre-pass: blocks [0,8192) = per-row absmax quantize x fp32->int8;
// blocks [8192,8704) = unpack int4 (byte-per-int32) -> int8 [O][I]
// ---------------------------------------------------------------------------
static __device__ __forceinline__ u32 pack4(float4 v, float inv) {
    int q0 = __float2int_rn(v.x * inv) & 255;
    int q1 = __float2int_rn(v.y * inv) & 255;
    int q2 = __float2int_rn(v.z * inv) & 255;
    int q3 = __float2int_rn(v.w * inv) & 255;
    return (u32)q0 | ((u32)q1 << 8) | ((u32)q2 << 16) | ((u32)q3 << 24);
}

__global__ __launch_bounds__(256) void prep_kernel(const float* __restrict__ x,
                                                   const int* __restrict__ pw,
                                                   s8* __restrict__ xq,
                                                   float* __restrict__ sx,
                                                   s8* __restrict__ wq) {
    __shared__ float red[4];
    int bid = blockIdx.x;
    int t = threadIdx.x;
    if (bid < M_TOK) {
        int row = bid;
        const float4* xr = (const float4*)(x + (size_t)row * K_IN);
        float4 v0 = xr[t], v1 = xr[t + 256], v2 = xr[t + 512], v3 = xr[t + 768];
        float am = 0.f;
        am = fmaxf(am, fmaxf(fmaxf(fabsf(v0.x), fabsf(v0.y)), fmaxf(fabsf(v0.z), fabsf(v0.w))));
        am = fmaxf(am, fmaxf(fmaxf(fabsf(v1.x), fabsf(v1.y)), fmaxf(fabsf(v1.z), fabsf(v1.w))));
        am = fmaxf(am, fmaxf(fmaxf(fabsf(v2.x), fabsf(v2.y)), fmaxf(fabsf(v2.z), fabsf(v2.w))));
        am = fmaxf(am, fmaxf(fmaxf(fabsf(v3.x), fabsf(v3.y)), fmaxf(fabsf(v3.z), fabsf(v3.w))));
#pragma unroll
        for (int o = 32; o > 0; o >>= 1) am = fmaxf(am, __shfl_xor(am, o));
        if ((t & 63) == 0) red[t >> 6] = am;
        __syncthreads();
        am = fmaxf(fmaxf(red[0], red[1]), fmaxf(red[2], red[3]));
        float inv = (am > 0.f) ? 127.f / am : 0.f;
        if (t == 0) sx[row] = (am > 0.f) ? am / 127.f : 0.f;
        u32* out = (u32*)(xq + (size_t)row * K_IN);
        out[t]       = pack4(v0, inv);
        out[t + 256] = pack4(v1, inv);
        out[t + 512] = pack4(v2, inv);
        out[t + 768] = pack4(v3, inv);
    } else {
        const int n4 = (N_OUT * K_IN / 2) / 4;
        int idx = (bid - M_TOK) * 256 + t;
        const int stride = 512 * 256;
        for (int i = idx; i < n4; i += stride) {
            int4 p = *(const int4*)(pw + (size_t)i * 4);
            u32 lo = (u32)(((p.x & 15) - 8) & 255)
                   | ((u32)((((p.x >> 4) & 15) - 8) & 255) << 8)
                   | ((u32)((((p.y) & 15) - 8) & 255) << 16)
                   | ((u32)((((p.y >> 4) & 15) - 8) & 255) << 24);
            u32 hi = (u32)(((p.z & 15) - 8) & 255)
                   | ((u32)((((p.z >> 4) & 15) - 8) & 255) << 8)
                   | ((u32)((((p.w) & 15) - 8) & 255) << 16)
                   | ((u32)((((p.w >> 4) & 15) - 8) & 255) << 24);
            uint2 o; o.x = lo; o.y = hi;
            *(uint2*)(wq + (size_t)i * 8) = o;
        }
    }
}

// ---------------------------------------------------------------------------
// 256x256 int8 GEMM, round-9 schedule, mfma_i32_32x32x32_i8 (4404 TOPS shape).
// C[n][o] = sx[n] * scale[o] * sum_k xq[n][k]*wq[o][k]
// LDS: row-major [256][128] i8 per region, 16B-slot swizzle slot ^= (row&7).
// Wave tile 128x64 = 4m x 2n of 32x32; K-tile 128 = 4 MFMA k-steps.
// ---------------------------------------------------------------------------
#define MFMA32(a, b, c) __builtin_amdgcn_mfma_i32_32x32x32_i8(a, b, c, 0, 0, 0)

static __device__ __forceinline__ i32x4 ldsv(const u8* p, int idx) {
    return *(const i32x4*)(p + idx);
}

// 16 MFMA: two m-groups x 2 n x 4 k-steps; same-acc dep distance = 4
#define BURST(P0, P1, P2, P3, Q0, Q1, Q2, Q3, M0, M1)     \
    acc[M0][0] = MFMA32(P0, b00, acc[M0][0]);             \
    acc[M0][1] = MFMA32(P0, b10, acc[M0][1]);             \
    acc[M1][0] = MFMA32(Q0, b00, acc[M1][0]);             \
    acc[M1][1] = MFMA32(Q0, b10, acc[M1][1]);             \
    acc[M0][0] = MFMA32(P1, b01, acc[M0][0]);             \
    acc[M0][1] = MFMA32(P1, b11, acc[M0][1]);             \
    acc[M1][0] = MFMA32(Q1, b01, acc[M1][0]);             \
    acc[M1][1] = MFMA32(Q1, b11, acc[M1][1]);             \
    acc[M0][0] = MFMA32(P2, b02, acc[M0][0]);             \
    acc[M0][1] = MFMA32(P2, b12, acc[M0][1]);             \
    acc[M1][0] = MFMA32(Q2, b02, acc[M1][0]);             \
    acc[M1][1] = MFMA32(Q2, b12, acc[M1][1]);             \
    acc[M0][0] = MFMA32(P3, b03, acc[M0][0]);             \
    acc[M0][1] = MFMA32(P3, b13, acc[M0][1]);             \
    acc[M1][0] = MFMA32(Q3, b03, acc[M1][0]);             \
    acc[M1][1] = MFMA32(Q3, b13, acc[M1][1]);

__global__ __launch_bounds__(512, 2) void gemm32_i8_kernel(const s8* __restrict__ A,
                                                           const s8* __restrict__ B,
                                                           const float* __restrict__ sx,
                                                           const float* __restrict__ scale,
                                                           float* __restrict__ C) {
    __shared__ __align__(16) u8 lds[131072];

#define GLo(src, dstIdx)                                                        \
    __builtin_amdgcn_global_load_lds(                                           \
        (const __attribute__((address_space(1))) void*)(src),                   \
        (__attribute__((address_space(3))) void*)&lds[dstIdx], 16, 0, 0)

    int wg = blockIdx.x;
    int swz = (wg & 7) * 64 + (wg >> 3);
    int bm = swz >> 4;
    int bn = swz & 15;

    int t = threadIdx.x;
    int l = t & 63;
    int wid = t >> 6;
    int wr = wid >> 2;       // 0..1  (128-row slab of A)
    int wc = wid & 3;        // 0..3  (64-row slab of B)

    // staging (identical to round 9): linear LDS dest, inverse-swizzled source
    const size_t soff = (size_t)(t >> 3) * K_IN + (size_t)((((t & 7) ^ ((t >> 3) & 7)) << 4));
    const size_t S64 = (size_t)64 * K_IN;
    const int t16 = t * 16;

    const s8* Alo = A + (size_t)(bm * 256) * K_IN;
    const s8* Ahi = Alo + (size_t)128 * K_IN;
    const s8* Blo = B + (size_t)(bn * 256) * K_IN;
    const s8* Bhi = Blo + (size_t)128 * K_IN;

    // read addressing: row = l&31; k-byte = (l>>5)*16 + 32*ks, slot ^= (l&7)
    const int ks0 = ((((l >> 5) + 0) ^ (l & 7)) << 4);
    const int ks1 = ((((l >> 5) + 2) ^ (l & 7)) << 4);
    const int ks2 = ((((l >> 5) + 4) ^ (l & 7)) << 4);
    const int ks3 = ((((l >> 5) + 6) ^ (l & 7)) << 4);
    const int aB = wr * 16384 + (l & 31) * 128;           // A region (m*4096 per group)
    const int bB = 32768 + wc * 8192 + (l & 31) * 128;    // B region (n*4096 per group)

    i32x16 acc[4][2] = {};

    // ---- prologue: B(0),A(0) -> buf0; B(1) -> buf1 ----
    GLo(Blo + soff, 32768 + t16);         GLo(Blo + soff + S64, 32768 + t16 + 8192);
    GLo(Bhi + soff, 49152 + t16);         GLo(Bhi + soff + S64, 49152 + t16 + 8192);
    GLo(Alo + soff, t16);                 GLo(Alo + soff + S64, t16 + 8192);
    GLo(Ahi + soff, 16384 + t16);         GLo(Ahi + soff + S64, 16384 + t16 + 8192);
    GLo(Blo + soff + 128, 98304 + t16);   GLo(Blo + soff + S64 + 128, 98304 + t16 + 8192);
    GLo(Bhi + soff + 128, 114688 + t16);  GLo(Bhi + soff + S64 + 128, 114688 + t16 + 8192);
    asm volatile("s_waitcnt vmcnt(4)" ::: "memory");
    __builtin_amdgcn_s_barrier();

    for (int T = 0; T < NT; ++T) {
        const int buf = T & 1;
        const u8* L = lds + buf * 65536;

        // ---- reads: all B (8) + A m0 (P), m1 (Q) ----
        i32x4 b00 = ldsv(L, bB + ks0),        b01 = ldsv(L, bB + ks1);
        i32x4 b02 = ldsv(L, bB + ks2),        b03 = ldsv(L, bB + ks3);
        i32x4 b10 = ldsv(L, bB + 4096 + ks0), b11 = ldsv(L, bB + 4096 + ks1);
        i32x4 b12 = ldsv(L, bB + 4096 + ks2), b13 = ldsv(L, bB + 4096 + ks3);
        i32x4 aP0 = ldsv(L, aB + ks0),        aP1 = ldsv(L, aB + ks1);
        i32x4 aP2 = ldsv(L, aB + ks2),        aP3 = ldsv(L, aB + ks3);
        i32x4 aQ0 = ldsv(L, aB + 4096 + ks0), aQ1 = ldsv(L, aB + 4096 + ks1);
        i32x4 aQ2 = ldsv(L, aB + 4096 + ks2), aQ3 = ldsv(L, aB + 4096 + ks3);

        // ---- stage A(T+1) -> other buffer ----
        if (T + 1 < NT) {
            size_t ko = (size_t)(T + 1) * 128;
            int d = (buf ^ 1) * 65536 + t16;
            GLo(Alo + soff + ko, d);                 GLo(Alo + soff + S64 + ko, d + 8192);
            GLo(Ahi + soff + ko, d + 16384);         GLo(Ahi + soff + S64 + ko, d + 24576);
        }

        // ---- reads: A m2 (R), m3 (S) — complete under burst1 ----
        i32x4 aR0 = ldsv(L, aB + 8192 + ks0),  aR1 = ldsv(L, aB + 8192 + ks1);
        i32x4 aR2 = ldsv(L, aB + 8192 + ks2),  aR3 = ldsv(L, aB + 8192 + ks3);
        i32x4 aS0 = ldsv(L, aB + 12288 + ks0), aS1 = ldsv(L, aB + 12288 + ks1);
        i32x4 aS2 = ldsv(L, aB + 12288 + ks2), aS3 = ldsv(L, aB + 12288 + ks3);

        __builtin_amdgcn_s_setprio(1);
        BURST(aP0, aP1, aP2, aP3, aQ0, aQ1, aQ2, aQ3, 0, 1);
        __builtin_amdgcn_s_setprio(0);

        // ---- barrier #1: all waves consumed their B reads -> B region free ----
        __builtin_amdgcn_s_barrier();
        asm volatile("" ::: "memory");

        if (T + 2 < NT) {
            size_t ko = (size_t)(T + 2) * 128;
            int d = buf * 65536 + 32768 + t16;
            GLo(Blo + soff + ko, d);          GLo(Blo + soff + S64 + ko, d + 8192);
            GLo(Bhi + soff + ko, d + 16384);  GLo(Bhi + soff + S64 + ko, d + 24576);
        }

        __builtin_amdgcn_s_setprio(1);
        BURST(aR0, aR1, aR2, aR3, aS0, aS1, aS2, aS3, 2, 3);
        __builtin_amdgcn_s_setprio(0);

        // ---- boundary: drain B(T+1)+A(T+1), keep B(T+2) in flight ----
        if (T < NT - 2) asm volatile("s_waitcnt vmcnt(4)" ::: "memory");
        else            asm volatile("s_waitcnt vmcnt(0)" ::: "memory");
        __builtin_amdgcn_s_barrier();
    }

    // ---- epilogue: C/D 32x32 layout col = lane&31, row = (reg&3)+8(reg>>2)+4(lane>>5)
    int col0 = bn * 256 + wc * 64 + (l & 31);
    float scA = scale[col0];
    float scB = scale[col0 + 32];

#pragma unroll
    for (int m = 0; m < 4; ++m) {
#pragma unroll
        for (int g = 0; g < 4; ++g) {
            int row0 = bm * 256 + wr * 128 + m * 32 + g * 8 + (l >> 5) * 4;
            float4 sxr = *(const float4*)(sx + row0);
            float sxa[4] = {sxr.x, sxr.y, sxr.z, sxr.w};
#pragma unroll
            for (int j = 0; j < 4; ++j) {
                C[(size_t)(row0 + j) * N_OUT + col0]      = (float)acc[m][0][g * 4 + j] * sxa[j] * scA;
                C[(size_t)(row0 + j) * N_OUT + col0 + 32] = (float)acc[m][1][g * 4 + j] * sxa[j] * scB;
            }
        }
    }
#undef GLo
}

// ---------------------------------------------------------------------------
// Fallback (workspace too small): fused fp32 LDS-tiled GEMM
// ---------------------------------------------------------------------------
__global__ __launch_bounds__(256) void gemm_fb_kernel(const float* __restrict__ X,
                                                      const int* __restrict__ PW,
                                                      const float* __restrict__ S,
                                                      float* __restrict__ C) {
    __shared__ float sxm[64][33];
    __shared__ float swm[64][33];
    int bm = blockIdx.x / (N_OUT / 64);
    int bn = blockIdx.x % (N_OUT / 64);
    int t = threadIdx.x;
    int r = t >> 2, c8 = (t & 3) * 8;
    int tx = t & 15, ty = t >> 4;
    float acc[4][4] = {};
    for (int k0 = 0; k0 < K_IN; k0 += 32) {
        const float* xs = X + (size_t)(bm * 64 + r) * K_IN + k0 + c8;
#pragma unroll
        for (int j = 0; j < 8; ++j) sxm[r][c8 + j] = xs[j];
        const int* ps = PW + ((size_t)(bn * 64 + r) * K_IN + k0 + c8) / 2;
#pragma unroll
        for (int j = 0; j < 4; ++j) {
            int b = ps[j];
            swm[r][c8 + 2 * j]     = (float)((b & 15) - 8);
            swm[r][c8 + 2 * j + 1] = (float)(((b >> 4) & 15) - 8);
        }
        __syncthreads();
#pragma unroll
        for (int kk = 0; kk < 32; ++kk) {
            float a[4], w[4];
#pragma unroll
            for (int i = 0; i < 4; ++i) a[i] = sxm[ty * 4 + i][kk];
#pragma unroll
            for (int j = 0; j < 4; ++j) w[j] = swm[tx * 4 + j][kk];
#pragma unroll
            for (int i = 0; i < 4; ++i)
#pragma unroll
                for (int j = 0; j < 4; ++j) acc[i][j] += a[i] * w[j];
        }
        __syncthreads();
    }
#pragma unroll
    for (int i = 0; i < 4; ++i) {
        int gr = bm * 64 + ty * 4 + i;
#pragma unroll
        for (int j = 0; j < 4; ++j) {
            int gc = bn * 64 + tx * 4 + j;
            C[(size_t)gr * N_OUT + gc] = acc[i][j] * S[gc];
        }
    }
}

// ---------------------------------------------------------------------------
// Entry point
// ---------------------------------------------------------------------------
extern "C" void kernel_launch(void* const* d_in, const int* in_sizes, int n_in,
                              void* d_out, int out_size, void* d_ws, size_t ws_size,
                              hipStream_t stream) {
    const float* x  = (const float*)d_in[0];
    const int*   pw = (const int*)d_in[1];
    const float* sc = (const float*)d_in[2];
    float* out = (float*)d_out;

    const size_t xq_bytes = (size_t)M_TOK * K_IN;
    const size_t wq_bytes = (size_t)N_OUT * K_IN;
    const size_t sx_bytes = (size_t)M_TOK * sizeof(float);
    const size_t need = xq_bytes + wq_bytes + sx_bytes;

    if (ws_size >= need) {
        s8* xq = (s8*)d_ws;
        s8* wq = xq + xq_bytes;
        float* sx = (float*)(wq + wq_bytes);
        prep_kernel<<<dim3(M_TOK + 512), dim3(256), 0, stream>>>(x, pw, xq, sx, wq);
        gemm32_i8_kernel<<<dim3((M_TOK / 256) * (N_OUT / 256)), dim3(512), 0, stream>>>(
            xq, wq, sx, sc, out);
    } else {
        gemm_fb_kernel<<<dim3((M_TOK / 64) * (N_OUT / 64)), dim3(256), 0, stream>>>(x, pw, sc, out);
    }
}

// Round 13
// 169.474 us; speedup vs baseline: 1.2853x; 1.1273x over previous
//
#include <hip/hip_runtime.h>

typedef unsigned char u8;
typedef signed char s8;
typedef unsigned int u32;
typedef __attribute__((ext_vector_type(4))) int i32x4;

#define M_TOK 8192
#define N_OUT 4096
#define K_IN  4096
#define NT    32          // K-tiles of BK=128 int8

// ---------------------------------------------------------------------------
// Fused pre-pass (2560 blocks):
//   blocks [0,2048):    wave-per-row absmax quantize x fp32->int8 (4 rows/blk)
//   blocks [2048,2560): unpack int4 (byte-per-int32) -> int8 [O][I]
// ---------------------------------------------------------------------------
static __device__ __forceinline__ u32 pack4(float4 v, float inv) {
    int q0 = __float2int_rn(v.x * inv) & 255;
    int q1 = __float2int_rn(v.y * inv) & 255;
    int q2 = __float2int_rn(v.z * inv) & 255;
    int q3 = __float2int_rn(v.w * inv) & 255;
    return (u32)q0 | ((u32)q1 << 8) | ((u32)q2 << 16) | ((u32)q3 << 24);
}

__global__ __launch_bounds__(256) void prep_kernel(const float* __restrict__ x,
                                                   const int* __restrict__ pw,
                                                   s8* __restrict__ xq,
                                                   float* __restrict__ sx,
                                                   s8* __restrict__ wq) {
    int bid = blockIdx.x;
    int t = threadIdx.x;
    if (bid < 2048) {
        // --- wave-per-row quantize: row = bid*4 + wave-id, no barriers ---
        int row = bid * 4 + (t >> 6);
        int ln = t & 63;
        const float4* xr = (const float4*)(x + (size_t)row * K_IN);
        float4 v[16];
        float am = 0.f;
#pragma unroll
        for (int j = 0; j < 16; ++j) {
            v[j] = xr[ln + j * 64];
            am = fmaxf(am, fmaxf(fmaxf(fabsf(v[j].x), fabsf(v[j].y)),
                                 fmaxf(fabsf(v[j].z), fabsf(v[j].w))));
        }
#pragma unroll
        for (int o = 32; o > 0; o >>= 1) am = fmaxf(am, __shfl_xor(am, o));
        float inv = (am > 0.f) ? 127.f / am : 0.f;
        if (ln == 0) sx[row] = (am > 0.f) ? am / 127.f : 0.f;
        u32* out = (u32*)(xq + (size_t)row * K_IN);
#pragma unroll
        for (int j = 0; j < 16; ++j) out[ln + j * 64] = pack4(v[j], inv);
    } else {
        // --- unpack weights: grid-stride over n4 = 2^21 groups of 4 ints ---
        const int n4 = (N_OUT * K_IN / 2) / 4;
        int idx = (bid - 2048) * 256 + t;
        const int stride = 512 * 256;
        for (int i = idx; i < n4; i += stride) {
            int4 p = *(const int4*)(pw + (size_t)i * 4);
            u32 lo = (u32)(((p.x & 15) - 8) & 255)
                   | ((u32)((((p.x >> 4) & 15) - 8) & 255) << 8)
                   | ((u32)((((p.y) & 15) - 8) & 255) << 16)
                   | ((u32)((((p.y >> 4) & 15) - 8) & 255) << 24);
            u32 hi = (u32)(((p.z & 15) - 8) & 255)
                   | ((u32)((((p.z >> 4) & 15) - 8) & 255) << 8)
                   | ((u32)((((p.w) & 15) - 8) & 255) << 16)
                   | ((u32)((((p.w >> 4) & 15) - 8) & 255) << 24);
            uint2 o; o.x = lo; o.y = hi;
            *(uint2*)(wq + (size_t)i * 8) = o;
        }
    }
}

// ---------------------------------------------------------------------------
// 256x256 int8 GEMM (round-9 schedule, verbatim): fine read-ahead interleave,
// counted lgkm via compiler dependency waits, 2 barriers/tile, counted vmcnt.
// C[n][o] = sx[n] * scale[o] * sum_k xq[n][k]*wq[o][k]
// LDS: row-major [256][128] i8 per region, byte ^= (row&7)<<4 swizzle.
// ---------------------------------------------------------------------------
#define MFMA(a, b, c) __builtin_amdgcn_mfma_i32_16x16x64_i8(a, b, c, 0, 0, 0)

static __device__ __forceinline__ i32x4 ldsv(const u8* p, int idx) {
    return *(const i32x4*)(p + idx);
}

#define MFMA16(A00, A01, A10, A11, M0, M1)                \
    acc[M0][0] = MFMA(A00, b00, acc[M0][0]);              \
    acc[M0][1] = MFMA(A00, b10, acc[M0][1]);              \
    acc[M0][2] = MFMA(A00, b20, acc[M0][2]);              \
    acc[M0][3] = MFMA(A00, b30, acc[M0][3]);              \
    acc[M1][0] = MFMA(A10, b00, acc[M1][0]);              \
    acc[M1][1] = MFMA(A10, b10, acc[M1][1]);              \
    acc[M1][2] = MFMA(A10, b20, acc[M1][2]);              \
    acc[M1][3] = MFMA(A10, b30, acc[M1][3]);              \
    acc[M0][0] = MFMA(A01, b01, acc[M0][0]);              \
    acc[M0][1] = MFMA(A01, b11, acc[M0][1]);              \
    acc[M0][2] = MFMA(A01, b21, acc[M0][2]);              \
    acc[M0][3] = MFMA(A01, b31, acc[M0][3]);              \
    acc[M1][0] = MFMA(A11, b01, acc[M1][0]);              \
    acc[M1][1] = MFMA(A11, b11, acc[M1][1]);              \
    acc[M1][2] = MFMA(A11, b21, acc[M1][2]);              \
    acc[M1][3] = MFMA(A11, b31, acc[M1][3]);

__global__ __launch_bounds__(512, 2) void gemmra_i8_kernel(const s8* __restrict__ A,
                                                           const s8* __restrict__ B,
                                                           const float* __restrict__ sx,
                                                           const float* __restrict__ scale,
                                                           float* __restrict__ C) {
    __shared__ __align__(16) u8 lds[131072];

#define GLo(src, dstIdx)                                                        \
    __builtin_amdgcn_global_load_lds(                                           \
        (const __attribute__((address_space(1))) void*)(src),                   \
        (__attribute__((address_space(3))) void*)&lds[dstIdx], 16, 0, 0)

    int wg = blockIdx.x;
    int swz = (wg & 7) * 64 + (wg >> 3);
    int bm = swz >> 4;
    int bn = swz & 15;

    int t = threadIdx.x;
    int l = t & 63;
    int wid = t >> 6;
    int wr = wid >> 2;
    int wc = wid & 3;

    const size_t soff = (size_t)(t >> 3) * K_IN + (size_t)((((t & 7) ^ ((t >> 3) & 7)) << 4));
    const size_t S64 = (size_t)64 * K_IN;
    const int t16 = t * 16;

    const s8* Alo = A + (size_t)(bm * 256) * K_IN;
    const s8* Ahi = Alo + (size_t)128 * K_IN;
    const s8* Blo = B + (size_t)(bn * 256) * K_IN;
    const s8* Bhi = Blo + (size_t)128 * K_IN;

    const int kx = (l & 7) << 4;
    const int koff0 = (((l >> 4) << 4)) ^ kx;
    const int koff1 = koff0 ^ 64;
    const int aB = wr * 16384 + (l & 15) * 128;
    const int bB = 32768 + wc * 8192 + (l & 15) * 128;

    i32x4 acc[8][4] = {};

    // ---- prologue: B(0),A(0) -> buf0; B(1) -> buf1 ----
    GLo(Blo + soff, 32768 + t16);         GLo(Blo + soff + S64, 32768 + t16 + 8192);
    GLo(Bhi + soff, 49152 + t16);         GLo(Bhi + soff + S64, 49152 + t16 + 8192);
    GLo(Alo + soff, t16);                 GLo(Alo + soff + S64, t16 + 8192);
    GLo(Ahi + soff, 16384 + t16);         GLo(Ahi + soff + S64, 16384 + t16 + 8192);
    GLo(Blo + soff + 128, 98304 + t16);   GLo(Blo + soff + S64 + 128, 98304 + t16 + 8192);
    GLo(Bhi + soff + 128, 114688 + t16);  GLo(Bhi + soff + S64 + 128, 114688 + t16 + 8192);
    asm volatile("s_waitcnt vmcnt(4)" ::: "memory");
    __builtin_amdgcn_s_barrier();

    for (int T = 0; T < NT; ++T) {
        const int buf = T & 1;
        const u8* L = lds + buf * 65536;

        // ---- group 1: all B + A m0,m1 ----
        i32x4 b00 = ldsv(L, bB + koff0),        b01 = ldsv(L, bB + koff1);
        i32x4 b10 = ldsv(L, bB + 2048 + koff0), b11 = ldsv(L, bB + 2048 + koff1);
        i32x4 b20 = ldsv(L, bB + 4096 + koff0), b21 = ldsv(L, bB + 4096 + koff1);
        i32x4 b30 = ldsv(L, bB + 6144 + koff0), b31 = ldsv(L, bB + 6144 + koff1);
        i32x4 p00 = ldsv(L, aB + koff0),        p01 = ldsv(L, aB + koff1);
        i32x4 p10 = ldsv(L, aB + 2048 + koff0), p11 = ldsv(L, aB + 2048 + koff1);

        // ---- stage A(T+1) -> other buffer ----
        if (T + 1 < NT) {
            size_t ko = (size_t)(T + 1) * 128;
            int d = (buf ^ 1) * 65536 + t16;
            GLo(Alo + soff + ko, d);                 GLo(Alo + soff + S64 + ko, d + 8192);
            GLo(Ahi + soff + ko, d + 16384);         GLo(Ahi + soff + S64 + ko, d + 24576);
        }

        // ---- read-ahead A m2,m3 (in flight under MFMA m0,m1) ----
        i32x4 q00 = ldsv(L, aB + 4096 + koff0), q01 = ldsv(L, aB + 4096 + koff1);
        i32x4 q10 = ldsv(L, aB + 6144 + koff0), q11 = ldsv(L, aB + 6144 + koff1);

        __builtin_amdgcn_s_setprio(1);
        MFMA16(p00, p01, p10, p11, 0, 1);
        __builtin_amdgcn_s_setprio(0);

        // ---- read-ahead A m4,m5 ----
        p00 = ldsv(L, aB + 8192 + koff0);  p01 = ldsv(L, aB + 8192 + koff1);
        p10 = ldsv(L, aB + 10240 + koff0); p11 = ldsv(L, aB + 10240 + koff1);

        __builtin_amdgcn_s_setprio(1);
        MFMA16(q00, q01, q10, q11, 2, 3);
        __builtin_amdgcn_s_setprio(0);

        // ---- barrier #1: every wave has consumed its B reads ----
        __builtin_amdgcn_s_barrier();
        asm volatile("" ::: "memory");

        if (T + 2 < NT) {
            size_t ko = (size_t)(T + 2) * 128;
            int d = buf * 65536 + 32768 + t16;
            GLo(Blo + soff + ko, d);          GLo(Blo + soff + S64 + ko, d + 8192);
            GLo(Bhi + soff + ko, d + 16384);  GLo(Bhi + soff + S64 + ko, d + 24576);
        }

        // ---- read-ahead A m6,m7 ----
        q00 = ldsv(L, aB + 12288 + koff0); q01 = ldsv(L, aB + 12288 + koff1);
        q10 = ldsv(L, aB + 14336 + koff0); q11 = ldsv(L, aB + 14336 + koff1);

        __builtin_amdgcn_s_setprio(1);
        MFMA16(p00, p01, p10, p11, 4, 5);
        MFMA16(q00, q01, q10, q11, 6, 7);
        __builtin_amdgcn_s_setprio(0);

        // ---- boundary: drain B(T+1)+A(T+1), keep B(T+2) in flight ----
        if (T < NT - 2) asm volatile("s_waitcnt vmcnt(4)" ::: "memory");
        else            asm volatile("s_waitcnt vmcnt(0)" ::: "memory");
        __builtin_amdgcn_s_barrier();
    }

    // ---- epilogue ----
    int col0 = bn * 256 + wc * 64 + (l & 15);
    float sc_[4];
#pragma unroll
    for (int n = 0; n < 4; ++n) sc_[n] = scale[col0 + n * 16];

#pragma unroll
    for (int m = 0; m < 8; ++m) {
        int row0 = bm * 256 + wr * 128 + m * 16 + (l >> 4) * 4;
        float4 sxr = *(const float4*)(sx + row0);
        float sxa[4] = {sxr.x, sxr.y, sxr.z, sxr.w};
#pragma unroll
        for (int n = 0; n < 4; ++n) {
            int gcol = col0 + n * 16;
#pragma unroll
            for (int j = 0; j < 4; ++j)
                C[(size_t)(row0 + j) * N_OUT + gcol] = (float)acc[m][n][j] * sxa[j] * sc_[n];
        }
    }
#undef GLo
}

// ---------------------------------------------------------------------------
// Fallback (workspace too small): fused fp32 LDS-tiled GEMM
// ---------------------------------------------------------------------------
__global__ __launch_bounds__(256) void gemm_fb_kernel(const float* __restrict__ X,
                                                      const int* __restrict__ PW,
                                                      const float* __restrict__ S,
                                                      float* __restrict__ C) {
    __shared__ float sxm[64][33];
    __shared__ float swm[64][33];
    int bm = blockIdx.x / (N_OUT / 64);
    int bn = blockIdx.x % (N_OUT / 64);
    int t = threadIdx.x;
    int r = t >> 2, c8 = (t & 3) * 8;
    int tx = t & 15, ty = t >> 4;
    float acc[4][4] = {};
    for (int k0 = 0; k0 < K_IN; k0 += 32) {
        const float* xs = X + (size_t)(bm * 64 + r) * K_IN + k0 + c8;
#pragma unroll
        for (int j = 0; j < 8; ++j) sxm[r][c8 + j] = xs[j];
        const int* ps = PW + ((size_t)(bn * 64 + r) * K_IN + k0 + c8) / 2;
#pragma unroll
        for (int j = 0; j < 4; ++j) {
            int b = ps[j];
            swm[r][c8 + 2 * j]     = (float)((b & 15) - 8);
            swm[r][c8 + 2 * j + 1] = (float)(((b >> 4) & 15) - 8);
        }
        __syncthreads();
#pragma unroll
        for (int kk = 0; kk < 32; ++kk) {
            float a[4], w[4];
#pragma unroll
            for (int i = 0; i < 4; ++i) a[i] = sxm[ty * 4 + i][kk];
#pragma unroll
            for (int j = 0; j < 4; ++j) w[j] = swm[tx * 4 + j][kk];
#pragma unroll
            for (int i = 0; i < 4; ++i)
#pragma unroll
                for (int j = 0; j < 4; ++j) acc[i][j] += a[i] * w[j];
        }
        __syncthreads();
    }
#pragma unroll
    for (int i = 0; i < 4; ++i) {
        int gr = bm * 64 + ty * 4 + i;
#pragma unroll
        for (int j = 0; j < 4; ++j) {
            int gc = bn * 64 + tx * 4 + j;
            C[(size_t)gr * N_OUT + gc] = acc[i][j] * S[gc];
        }
    }
}

// ---------------------------------------------------------------------------
// Entry point
// ---------------------------------------------------------------------------
extern "C" void kernel_launch(void* const* d_in, const int* in_sizes, int n_in,
                              void* d_out, int out_size, void* d_ws, size_t ws_size,
                              hipStream_t stream) {
    const float* x  = (const float*)d_in[0];
    const int*   pw = (const int*)d_in[1];
    const float* sc = (const float*)d_in[2];
    float* out = (float*)d_out;

    const size_t xq_bytes = (size_t)M_TOK * K_IN;
    const size_t wq_bytes = (size_t)N_OUT * K_IN;
    const size_t sx_bytes = (size_t)M_TOK * sizeof(float);
    const size_t need = xq_bytes + wq_bytes + sx_bytes;

    if (ws_size >= need) {
        s8* xq = (s8*)d_ws;
        s8* wq = xq + xq_bytes;
        float* sx = (float*)(wq + wq_bytes);
        prep_kernel<<<dim3(2560), dim3(256), 0, stream>>>(x, pw, xq, sx, wq);
        gemmra_i8_kernel<<<dim3((M_TOK / 256) * (N_OUT / 256)), dim3(512), 0, stream>>>(
            xq, wq, sx, sc, out);
    } else {
        gemm_fb_kernel<<<dim3((M_TOK / 64) * (N_OUT / 64)), dim3(256), 0, stream>>>(x, pw, sc, out);
    }
}